// Round 4
// baseline (1858.021 us; speedup 1.0000x reference)
//
#include <hip/hip_runtime.h>
#include <hip/hip_fp16.h>

typedef _Float16 f16;
typedef _Float16 f16x8 __attribute__((ext_vector_type(8)));
typedef float f32x4 __attribute__((ext_vector_type(4)));

#define BB 4
#define TT 16
#define HH 64
#define WW 64
#define CC 32
#define FF 64
#define GG 256  // 4F gates

__device__ __forceinline__ float hsig(float z) {
    return fminf(fmaxf(0.2f * z + 0.5f, 0.f), 1.f);
}
__device__ __forceinline__ float tanh_fast(float x) {
    return 1.f - 2.f / (__expf(2.f * x) + 1.f);
}

__device__ __forceinline__ void async_copy16(const void* g, void* l) {
    __builtin_amdgcn_global_load_lds(
        (const __attribute__((address_space(1))) unsigned*)g,
        (__attribute__((address_space(3))) unsigned*)l, 16, 0, 0);
}

// ---------------- LayerNorm over C=32: fp32 in -> fp16 out ----------------
__global__ void ln_kernel(const float* __restrict__ x,
                          const float* __restrict__ gamma,
                          const float* __restrict__ beta,
                          f16* __restrict__ xn) {
    __shared__ float sg[CC], sb[CC];
    if (threadIdx.x < CC) sg[threadIdx.x] = gamma[threadIdx.x];
    else if (threadIdx.x < 2 * CC) sb[threadIdx.x - CC] = beta[threadIdx.x - CC];
    __syncthreads();
    int q = blockIdx.x * 256 + threadIdx.x;  // pixel < B*T*H*W = 262144
    const float* xp = x + (size_t)q * CC;
    float v[CC];
    float s = 0.f, s2 = 0.f;
#pragma unroll
    for (int c = 0; c < CC; c += 4) {
        float4 t4 = *(const float4*)(xp + c);
        v[c] = t4.x; v[c + 1] = t4.y; v[c + 2] = t4.z; v[c + 3] = t4.w;
        s += t4.x + t4.y + t4.z + t4.w;
        s2 += t4.x * t4.x + t4.y * t4.y + t4.z * t4.z + t4.w * t4.w;
    }
    float mu = s * (1.f / CC);
    float var = s2 * (1.f / CC) - mu * mu;
    float rs = rsqrtf(var + 1e-3f);
    f16 o[CC];
#pragma unroll
    for (int c = 0; c < CC; c++)
        o[c] = (f16)((v[c] - mu) * rs * sg[c] + sb[c]);
    f16x8* d = (f16x8*)(xn + (size_t)q * CC);
#pragma unroll
    for (int c = 0; c < 4; c++) d[c] = *(f16x8*)&o[c * 8];
}

// --- Weight prep: wslab[nh][phase][row][104] f16, phase-blocked, row stride padded ---
// row<->gate: g = (row>>5)*64 + nh*32 + (row&31). piece [0,96): chunk cw=piece/32, j=piece%32.
// chunk c = phase*3+cw: c<9 -> Wx k=c*32+j; c>=9 -> Wh k=(c-9)*32+j. piece>=96 -> 0 pad.
__global__ void wprep_kernel(const float* __restrict__ wx, const float* __restrict__ wh,
                             f16* __restrict__ wslab) {
    int e = blockIdx.x * 256 + threadIdx.x;
    if (e >= 2 * 9 * 128 * 104) return;
    int piece = e % 104;
    int r = e / 104;
    int row = r & 127;
    int p = (r >> 7) % 9;
    int nh = r / (9 * 128);
    float v = 0.f;
    if (piece < 96) {
        int c = p * 3 + piece / 32;
        int j = piece & 31;
        int g = ((row >> 5) << 6) + (nh << 5) + (row & 31);
        if (c < 9) v = wx[(c * 32 + j) * 256 + g];
        else       v = wh[((c - 9) * 32 + j) * 256 + g];
    }
    wslab[e] = (f16)v;
}

__device__ __forceinline__ void stage_xpatch(const f16* xslice, f16* xpatch,
                                             int tid, int ty, int tx) {
    if (tid < 200) {
        int pix = tid >> 1, part = tid & 1;
        int py = pix / 10, px = pix % 10;
        int y = ty * 8 - 1 + py, x = tx * 8 - 1 + px;
        f16x8* d = (f16x8*)&xpatch[pix * 40 + part * 16];
        if (y >= 0 && y < HH && x >= 0 && x < WW) {
            const f16x8* s = (const f16x8*)(xslice + ((size_t)y * WW + x) * CC + part * 16);
            d[0] = s[0]; d[1] = s[1];
        } else {
            f16x8 z = {0, 0, 0, 0, 0, 0, 0, 0};
            d[0] = z; d[1] = z;
        }
    }
}

__device__ __forceinline__ void stage_hpatch(const f16* hr, f16* hpatch,
                                             int tid, int bb, int ty, int tx) {
    if (tid < 200) {
        int pix = tid >> 1, part = tid & 1;
        int py = pix / 10, px = pix % 10;
        int y = ty * 8 - 1 + py, x = tx * 8 - 1 + px;
        f16x8* d = (f16x8*)&hpatch[pix * 72 + part * 32];
        if (y >= 0 && y < HH && x >= 0 && x < WW) {
            const f16x8* s = (const f16x8*)(hr + ((size_t)(bb * HH + y) * WW + x) * FF + part * 32);
            d[0] = s[0]; d[1] = s[1]; d[2] = s[2]; d[3] = s[3];
        } else {
            f16x8 z = {0, 0, 0, 0, 0, 0, 0, 0};
            d[0] = z; d[1] = z; d[2] = z; d[3] = z;
        }
    }
}

// ---------------- Persistent fused ConvLSTM: all 16 steps in one launch ----------------
// Grid: 512 = 256 px-tiles x 2 gate-halves (exactly 2 blocks/CU, LDS 75.6KB). Block: 256.
// Wave (wm,wn): 32 px x 64 gates. acc[2][4]; c-state lives in 8 VGPRs for all 16 steps.
__global__ __launch_bounds__(256, 2)
void lstm_kernel(const f16* __restrict__ xn, const f16* __restrict__ wslab,
                 const float* __restrict__ bs, f16* __restrict__ hs,
                 float* __restrict__ out, unsigned* __restrict__ bar) {
    __shared__ __align__(16) f16 xpatch[100 * 40];   //  8.0 KB
    __shared__ __align__(16) f16 hpatch[100 * 72];   // 14.4 KB
    __shared__ __align__(16) f16 wbuf[2 * 13312];    // 53.25 KB: 128 rows x 104 f16 / phase
    f16* hstage = &wbuf[13312];                      // epilogue reuse: 64 px x 40 f16

    int tile = blockIdx.x >> 1, nhalf = blockIdx.x & 1;
    int bb = tile >> 6, ty = (tile >> 3) & 7, tx = tile & 7;
    int tid = threadIdx.x;
    int lane = tid & 63, w = tid >> 6;
    int wm = w >> 1, wn = w & 1;
    int quad = lane >> 4, noff = lane & 15;

    const char* wsrc = (const char*)(wslab + (size_t)nhalf * (9 * 128 * 104));
    int fch = (nhalf << 5) + (wn << 4) + noff;  // f-channel in [0,64)
    float b_i = bs[fch], b_f = bs[64 + fch], b_c = bs[128 + fch], b_o = bs[192 + fch];

    float creg[8];
#pragma unroll
    for (int i = 0; i < 8; i++) creg[i] = 0.f;

    // phase-0 weights for t=0 into buf0; xpatch for t=0
#pragma unroll
    for (int c0 = w; c0 < 26; c0 += 4)
        async_copy16(wsrc + c0 * 1024 + (lane << 4), &wbuf[c0 * 512]);
    stage_xpatch(xn + (size_t)(bb * TT + 0) * (HH * WW) * CC, xpatch, tid, ty, tx);

    for (int t = 0; t < TT; t++) {
        int rslot = t & 1;
        const f16* hr = hs + (size_t)rslot * (BB * HH * WW * FF);
        f16* hw = hs + (size_t)(1 - rslot) * (BB * HH * WW * FF);

        stage_hpatch(hr, hpatch, tid, bb, ty, tx);

        f32x4 acc[2][4];
#pragma unroll
        for (int i = 0; i < 2; i++)
#pragma unroll
            for (int j = 0; j < 4; j++) acc[i][j] = (f32x4){0.f, 0.f, 0.f, 0.f};

        for (int p = 0; p < 9; ++p) {
            __syncthreads();  // drains vmcnt (weights ready) + lgkm (patch writes)
            if (p < 8) {
                const char* ws_p = wsrc + (p + 1) * 26624;
                f16* dst = &wbuf[((p + 1) & 1) * 13312];
#pragma unroll
                for (int c = w; c < 26; c += 4)
                    async_copy16(ws_p + c * 1024 + (lane << 4), dst + c * 512);
            }
            const f16* wb = &wbuf[(p & 1) * 13312];
#pragma unroll
            for (int cw = 0; cw < 3; ++cw) {
                int c = p * 3 + cw;
                bool isx = c < 9;
                int hc = c - 9;
                int tap = isx ? c : (hc >> 1);
                int coff = isx ? 0 : ((hc & 1) << 5);
                const f16* ap = isx ? xpatch : hpatch;
                int stride = isx ? 40 : 72;
                int dy = tap / 3, dx = tap % 3;
                f16x8 a[2];
#pragma unroll
                for (int mt = 0; mt < 2; mt++) {
                    int m = (wm << 5) + (mt << 4) + noff;
                    int pp = ((m >> 3) + dy) * 10 + (m & 7) + dx;
                    a[mt] = *(const f16x8*)&ap[pp * stride + coff + (quad << 3)];
                }
#pragma unroll
                for (int cls = 0; cls < 4; cls++) {
                    f16x8 bf = *(const f16x8*)&wb[((cls << 5) + (wn << 4) + noff) * 104 + (cw << 5) + (quad << 3)];
                    acc[0][cls] = __builtin_amdgcn_mfma_f32_16x16x32_f16(a[0], bf, acc[0][cls], 0, 0, 0);
                    acc[1][cls] = __builtin_amdgcn_mfma_f32_16x16x32_f16(a[1], bf, acc[1][cls], 0, 0, 0);
                }
            }
        }

        // ---- epilogue: gates + state (c in registers); h -> LDS repack ----
        int fchL = (wn << 4) + noff;  // local f-channel [0,32)
#pragma unroll
        for (int mt = 0; mt < 2; mt++) {
#pragma unroll
            for (int r = 0; r < 4; r++) {
                int m = (wm << 5) + (mt << 4) + (quad << 2) + r;  // C/D row = quad*4+reg
                float zi = acc[mt][0][r] + b_i;
                float zf = acc[mt][1][r] + b_f;
                float zc = acc[mt][2][r] + b_c;
                float zo = acc[mt][3][r] + b_o;
                float ig = hsig(zi), fg = hsig(zf), og = hsig(zo);
                float cn = fg * creg[mt * 4 + r] + ig * tanh_fast(zc);
                creg[mt * 4 + r] = cn;
                hstage[m * 40 + fchL] = (f16)(og * tanh_fast(cn));
            }
        }
        __syncthreads();  // hstage complete (also: all phase-8 wbuf reads done)

        // coalesced h write: 64 px x 32 f16 (this block's half)
        {
            int px = tid >> 2, part = tid & 3;
            int y = ty * 8 + (px >> 3), x = tx * 8 + (px & 7);
            f16x8 hv = *(const f16x8*)&hstage[px * 40 + part * 8];
            *(f16x8*)(hw + ((size_t)(bb * HH + y) * WW + x) * FF + (nhalf << 5) + part * 8) = hv;
        }
        // fused 2x2 maxpool: 16 out px x 32 fch
        {
            int opx = tid >> 4, fp = (tid & 15) * 2;
            int oy2 = opx >> 2, ox2 = opx & 3;
            int p00 = (oy2 * 2) * 8 + ox2 * 2;
            float2 mv;
            mv.x = fmaxf(fmaxf((float)hstage[p00 * 40 + fp], (float)hstage[(p00 + 1) * 40 + fp]),
                         fmaxf((float)hstage[(p00 + 8) * 40 + fp], (float)hstage[(p00 + 9) * 40 + fp]));
            mv.y = fmaxf(fmaxf((float)hstage[p00 * 40 + fp + 1], (float)hstage[(p00 + 1) * 40 + fp + 1]),
                         fmaxf((float)hstage[(p00 + 8) * 40 + fp + 1], (float)hstage[(p00 + 9) * 40 + fp + 1]));
            size_t oidx = ((size_t)((bb * TT + t) * 32 + ty * 4 + oy2) * 32 + tx * 4 + ox2) * 64
                        + (nhalf << 5) + fp;
            *(float2*)(out + oidx) = mv;
        }

        if (t < TT - 1) {
            // prefetch next step's phase-0 weights + xpatch BEFORE the barrier wait
#pragma unroll
            for (int c = w; c < 26; c += 4)
                async_copy16(wsrc + c * 1024 + (lane << 4), &wbuf[c * 512]);
            stage_xpatch(xn + (size_t)(bb * TT + t + 1) * (HH * WW) * CC, xpatch, tid, ty, tx);

            // ---- grid barrier (all 512 blocks co-resident by construction) ----
            __threadfence();
            __syncthreads();
            if (tid == 0) {
                unsigned old = __hip_atomic_load(&bar[1], __ATOMIC_RELAXED, __HIP_MEMORY_SCOPE_AGENT);
                unsigned a = __hip_atomic_fetch_add(&bar[0], 1u, __ATOMIC_ACQ_REL, __HIP_MEMORY_SCOPE_AGENT);
                if (a == gridDim.x - 1) {
                    __hip_atomic_store(&bar[0], 0u, __ATOMIC_RELAXED, __HIP_MEMORY_SCOPE_AGENT);
                    __hip_atomic_store(&bar[1], old + 1u, __ATOMIC_RELEASE, __HIP_MEMORY_SCOPE_AGENT);
                } else {
                    while (__hip_atomic_load(&bar[1], __ATOMIC_ACQUIRE, __HIP_MEMORY_SCOPE_AGENT) == old)
                        __builtin_amdgcn_s_sleep(2);
                }
            }
            __syncthreads();
        }
    }
}

extern "C" void kernel_launch(void* const* d_in, const int* in_sizes, int n_in,
                              void* d_out, int out_size, void* d_ws, size_t ws_size,
                              hipStream_t stream) {
    const float* x = (const float*)d_in[0];
    const float* gamma = (const float*)d_in[1];
    const float* beta = (const float*)d_in[2];
    const float* wx = (const float*)d_in[3];
    const float* wh = (const float*)d_in[4];
    const float* bs = (const float*)d_in[5];
    float* out = (float*)d_out;

    // workspace layout (16B-aligned); ~21.7 MB
    char* ws = (char*)d_ws;
    f16* xn = (f16*)ws;                        // 16,777,216 B
    f16* wslab = (f16*)(ws + 16777216);        // 2*9*128*104*2 = 479,232 B
    f16* hs = (f16*)(ws + 17256448);           // 2 x 2,097,152 B (ping-pong)
    unsigned* bar = (unsigned*)(ws + 21450752);  // 8 B barrier state

    hipMemsetAsync(hs, 0, (size_t)BB * HH * WW * FF * 2, stream);  // h0 = 0 (slot 0)
    hipMemsetAsync(bar, 0, 8, stream);                             // barrier reset

    ln_kernel<<<1024, 256, 0, stream>>>(x, gamma, beta, xn);
    wprep_kernel<<<936, 256, 0, stream>>>(wx, wh, wslab);
    lstm_kernel<<<512, 256, 0, stream>>>(xn, wslab, bs, hs, out, bar);
}

// Round 5
// 364.743 us; speedup vs baseline: 5.0941x; 5.0941x over previous
//
#include <hip/hip_runtime.h>
#include <hip/hip_fp16.h>

typedef _Float16 f16;
typedef _Float16 f16x8 __attribute__((ext_vector_type(8)));
typedef float f32x4 __attribute__((ext_vector_type(4)));

#define BB 4
#define TT 16
#define HH 64
#define WW 64
#define CC 32
#define FF 64
#define GG 256  // 4F gates

__device__ __forceinline__ float hsig(float z) {
    return fminf(fmaxf(0.2f * z + 0.5f, 0.f), 1.f);
}
__device__ __forceinline__ float tanh_fast(float x) {
    return 1.f - 2.f / (__expf(2.f * x) + 1.f);
}

__device__ __forceinline__ void async_copy16(const void* g, void* l) {
    __builtin_amdgcn_global_load_lds(
        (const __attribute__((address_space(1))) unsigned*)g,
        (__attribute__((address_space(3))) unsigned*)l, 16, 0, 0);
}

// ---------------- LayerNorm over C=32: fp32 in -> fp16 out ----------------
__global__ void ln_kernel(const float* __restrict__ x,
                          const float* __restrict__ gamma,
                          const float* __restrict__ beta,
                          f16* __restrict__ xn) {
    __shared__ float sg[CC], sb[CC];
    if (threadIdx.x < CC) sg[threadIdx.x] = gamma[threadIdx.x];
    else if (threadIdx.x < 2 * CC) sb[threadIdx.x - CC] = beta[threadIdx.x - CC];
    __syncthreads();
    int q = blockIdx.x * 256 + threadIdx.x;  // pixel < B*T*H*W = 262144
    const float* xp = x + (size_t)q * CC;
    float v[CC];
    float s = 0.f, s2 = 0.f;
#pragma unroll
    for (int c = 0; c < CC; c += 4) {
        float4 t4 = *(const float4*)(xp + c);
        v[c] = t4.x; v[c + 1] = t4.y; v[c + 2] = t4.z; v[c + 3] = t4.w;
        s += t4.x + t4.y + t4.z + t4.w;
        s2 += t4.x * t4.x + t4.y * t4.y + t4.z * t4.z + t4.w * t4.w;
    }
    float mu = s * (1.f / CC);
    float var = s2 * (1.f / CC) - mu * mu;
    float rs = rsqrtf(var + 1e-3f);
    f16 o[CC];
#pragma unroll
    for (int c = 0; c < CC; c++)
        o[c] = (f16)((v[c] - mu) * rs * sg[c] + sb[c]);
    f16x8* d = (f16x8*)(xn + (size_t)q * CC);
#pragma unroll
    for (int c = 0; c < 4; c++) d[c] = *(f16x8*)&o[c * 8];
}

// --- Weight prep: wslab[nh][phase][row][104] f16, phase-blocked, row stride padded ---
// row<->gate: g = (row>>5)*64 + nh*32 + (row&31). piece [0,96): chunk cw=piece/32, j=piece%32.
// chunk c = phase*3+cw: c<9 -> Wx k=c*32+j; c>=9 -> Wh k=(c-9)*32+j. piece>=96 -> 0 pad.
__global__ void wprep_kernel(const float* __restrict__ wx, const float* __restrict__ wh,
                             f16* __restrict__ wslab) {
    int e = blockIdx.x * 256 + threadIdx.x;
    if (e >= 2 * 9 * 128 * 104) return;
    int piece = e % 104;
    int r = e / 104;
    int row = r & 127;
    int p = (r >> 7) % 9;
    int nh = r / (9 * 128);
    float v = 0.f;
    if (piece < 96) {
        int c = p * 3 + piece / 32;
        int j = piece & 31;
        int g = ((row >> 5) << 6) + (nh << 5) + (row & 31);
        if (c < 9) v = wx[(c * 32 + j) * 256 + g];
        else       v = wh[((c - 9) * 32 + j) * 256 + g];
    }
    wslab[e] = (f16)v;
}

__device__ __forceinline__ void stage_xpatch(const f16* xslice, f16* xpatch,
                                             int tid, int ty, int tx) {
    if (tid < 200) {
        int pix = tid >> 1, part = tid & 1;
        int py = pix / 10, px = pix % 10;
        int y = ty * 8 - 1 + py, x = tx * 8 - 1 + px;
        f16x8* d = (f16x8*)&xpatch[pix * 40 + part * 16];
        if (y >= 0 && y < HH && x >= 0 && x < WW) {
            const f16x8* s = (const f16x8*)(xslice + ((size_t)y * WW + x) * CC + part * 16);
            d[0] = s[0]; d[1] = s[1];
        } else {
            f16x8 z = {0, 0, 0, 0, 0, 0, 0, 0};
            d[0] = z; d[1] = z;
        }
    }
}

__device__ __forceinline__ void stage_hpatch(const f16* hr, f16* hpatch,
                                             int tid, int bb, int ty, int tx) {
    if (tid < 200) {
        int pix = tid >> 1, part = tid & 1;
        int py = pix / 10, px = pix % 10;
        int y = ty * 8 - 1 + py, x = tx * 8 - 1 + px;
        f16x8* d = (f16x8*)&hpatch[pix * 72 + part * 32];
        if (y >= 0 && y < HH && x >= 0 && x < WW) {
            const f16x8* s = (const f16x8*)(hr + ((size_t)(bb * HH + y) * WW + x) * FF + part * 32);
            d[0] = s[0]; d[1] = s[1]; d[2] = s[2]; d[3] = s[3];
        } else {
            f16x8 z = {0, 0, 0, 0, 0, 0, 0, 0};
            d[0] = z; d[1] = z; d[2] = z; d[3] = z;
        }
    }
}

// ---------------- Fused step: z = conv(xn,Wx)+conv(h,Wh)+b; gates; state; pool ----------------
// Grid: 512 = 256 px-tiles x 2 gate-halves. Block: 256 (4 waves) -> 2 blocks/CU (LDS 75.6KB).
// Waves: wn (fch-16-half) x ks (K-split odd/even chunks). Wave tile: 64 px x 64 gates
// (4 M-tiles x 4 cls-tiles, acc[4][4] f32x4 = 64 VGPR). ks-pair acc reduction via LDS.
// cst layout: [tile][nhalf][wn][lane][16] -> fully coalesced b128 ld/st.
__global__ __launch_bounds__(256, 2)
void step_kernel(const f16* __restrict__ xn, const f16* __restrict__ wslab,
                 const float* __restrict__ bs,
                 float* __restrict__ cst, f16* __restrict__ hs,
                 float* __restrict__ out, int t) {
    __shared__ __align__(16) f16 xpatch[100 * 40];   //  8.0 KB
    __shared__ __align__(16) f16 hpatch[100 * 72];   // 14.4 KB
    __shared__ __align__(16) f16 wbuf[2 * 13312];    // 53.25 KB (reused: reduction + hstage)
    float* red = (float*)wbuf;                       // 128 rows x 68 dw = 34.8 KB
    f16* hstage = xpatch;                            // 64 px x 40 f16 = 5.1 KB

    int tile = blockIdx.x >> 1, nhalf = blockIdx.x & 1;
    int bb = tile >> 6, ty = (tile >> 3) & 7, tx = tile & 7;
    int tid = threadIdx.x;
    int lane = tid & 63, w = tid >> 6;
    int wn = w & 1, ks = w >> 1;
    int quad = lane >> 4, noff = lane & 15;

    const char* wsrc = (const char*)(wslab + (size_t)nhalf * (9 * 128 * 104));
    int rslot = t & 1;
    const f16* hr = hs + (size_t)rslot * (BB * HH * WW * FF);
    f16* hw = hs + (size_t)(1 - rslot) * (BB * HH * WW * FF);

    // phase-0 weight prefetch (26 x 1KB, spread over 4 waves)
    for (int c0 = w; c0 < 26; c0 += 4)
        async_copy16(wsrc + c0 * 1024 + (lane << 4), &wbuf[c0 * 512]);

    // stage patches (hpatch first: cross-launch dependency = critical path)
    stage_hpatch(hr, hpatch, tid, bb, ty, tx);
    stage_xpatch(xn + (size_t)(bb * TT + t) * (HH * WW) * CC, xpatch, tid, ty, tx);

    // coalesced c-state load (ks0 waves own the epilogue)
    size_t cbase = (size_t)tile * 4096 + (size_t)nhalf * 2048 + wn * 1024 + lane * 16;
    f32x4 cs[4];
#pragma unroll
    for (int j = 0; j < 4; j++) cs[j] = (f32x4){0.f, 0.f, 0.f, 0.f};
    if (ks == 0 && t > 0) {
#pragma unroll
        for (int j = 0; j < 4; j++) cs[j] = *(const f32x4*)(cst + cbase + j * 4);
    }

    int fch = (nhalf << 5) + (wn << 4) + noff;  // f-channel in [0,64)
    float b_i = bs[fch], b_f = bs[64 + fch], b_c = bs[128 + fch], b_o = bs[192 + fch];

    f32x4 acc[4][4];
#pragma unroll
    for (int i = 0; i < 4; i++)
#pragma unroll
        for (int j = 0; j < 4; j++) acc[i][j] = (f32x4){0.f, 0.f, 0.f, 0.f};

    for (int p = 0; p < 9; ++p) {
        __syncthreads();  // drains vmcnt (weights ready) + lgkm (patch/LDS writes)
        if (p < 8) {
            const char* ws_p = wsrc + (p + 1) * 26624;
            f16* dst = &wbuf[((p + 1) & 1) * 13312];
            for (int c = w; c < 26; c += 4)
                async_copy16(ws_p + c * 1024 + (lane << 4), dst + c * 512);
        }
        const f16* wb = &wbuf[(p & 1) * 13312];
#pragma unroll
        for (int cw = 0; cw < 3; ++cw) {
            int c = p * 3 + cw;
            if ((c & 1) != ks) continue;      // wave-uniform K-split
            bool isx = c < 9;
            int hc = c - 9;
            int tap = isx ? c : (hc >> 1);
            int coff = isx ? 0 : ((hc & 1) << 5);
            const f16* ap = isx ? xpatch : hpatch;
            int stride = isx ? 40 : 72;
            int dy = tap / 3, dx = tap % 3;
            f16x8 a[4];
#pragma unroll
            for (int mt = 0; mt < 4; mt++) {
                int m = (mt << 4) + noff;
                int pp = ((m >> 3) + dy) * 10 + (m & 7) + dx;
                a[mt] = *(const f16x8*)&ap[pp * stride + coff + (quad << 3)];
            }
#pragma unroll
            for (int cls = 0; cls < 4; cls++) {
                f16x8 bf = *(const f16x8*)&wb[((cls << 5) + (wn << 4) + noff) * 104 + (cw << 5) + (quad << 3)];
#pragma unroll
                for (int mt = 0; mt < 4; mt++)
                    acc[mt][cls] = __builtin_amdgcn_mfma_f32_16x16x32_f16(a[mt], bf, acc[mt][cls], 0, 0, 0);
            }
        }
    }

    // ---- ks-pair reduction via LDS (red aliases wbuf; all wbuf reads done) ----
    __syncthreads();
    if (ks == 1) {
        float* base = red + ((wn << 6) + lane) * 68;
#pragma unroll
        for (int mt = 0; mt < 4; mt++)
#pragma unroll
            for (int cls = 0; cls < 4; cls++)
                *(f32x4*)(base + ((mt << 2) + cls) * 4) = acc[mt][cls];
    }
    __syncthreads();

    // ---- epilogue on ks0 waves: gates + state; h -> hstage; coalesced cst store ----
    if (ks == 0) {
        const float* base = red + ((wn << 6) + lane) * 68;
#pragma unroll
        for (int mt = 0; mt < 4; mt++)
#pragma unroll
            for (int cls = 0; cls < 4; cls++)
                acc[mt][cls] += *(const f32x4*)(base + ((mt << 2) + cls) * 4);

        int fchL = (wn << 4) + noff;  // local f-channel [0,32)
#pragma unroll
        for (int mt = 0; mt < 4; mt++) {
            f32x4 cn4;
#pragma unroll
            for (int r = 0; r < 4; r++) {
                int m = (mt << 4) + (quad << 2) + r;  // C/D row = quad*4+reg
                float zi = acc[mt][0][r] + b_i;
                float zf = acc[mt][1][r] + b_f;
                float zc = acc[mt][2][r] + b_c;
                float zo = acc[mt][3][r] + b_o;
                float ig = hsig(zi), fg = hsig(zf), og = hsig(zo);
                float cn = fg * cs[mt][r] + ig * tanh_fast(zc);
                cn4[r] = cn;
                hstage[m * 40 + fchL] = (f16)(og * tanh_fast(cn));
            }
            *(f32x4*)(cst + cbase + mt * 4) = cn4;  // coalesced: lanes 64B apart
        }
    }
    __syncthreads();  // hstage complete

    // coalesced h write: 64 px x 32 f16 (this block's half)
    {
        int px = tid >> 2, part = tid & 3;
        int y = ty * 8 + (px >> 3), x = tx * 8 + (px & 7);
        f16x8 hv = *(const f16x8*)&hstage[px * 40 + part * 8];
        *(f16x8*)(hw + ((size_t)(bb * HH + y) * WW + x) * FF + (nhalf << 5) + part * 8) = hv;
    }
    // fused 2x2 maxpool: 16 out px x 32 fch -> fp32 out
    {
        int opx = tid >> 4, fp = (tid & 15) * 2;
        int oy2 = opx >> 2, ox2 = opx & 3;
        int p00 = (oy2 * 2) * 8 + ox2 * 2;
        float2 mv;
        mv.x = fmaxf(fmaxf((float)hstage[p00 * 40 + fp], (float)hstage[(p00 + 1) * 40 + fp]),
                     fmaxf((float)hstage[(p00 + 8) * 40 + fp], (float)hstage[(p00 + 9) * 40 + fp]));
        mv.y = fmaxf(fmaxf((float)hstage[p00 * 40 + fp + 1], (float)hstage[(p00 + 1) * 40 + fp + 1]),
                     fmaxf((float)hstage[(p00 + 8) * 40 + fp + 1], (float)hstage[(p00 + 9) * 40 + fp + 1]));
        size_t oidx = ((size_t)((bb * TT + t) * 32 + ty * 4 + oy2) * 32 + tx * 4 + ox2) * 64
                    + (nhalf << 5) + fp;
        *(float2*)(out + oidx) = mv;
    }
}

extern "C" void kernel_launch(void* const* d_in, const int* in_sizes, int n_in,
                              void* d_out, int out_size, void* d_ws, size_t ws_size,
                              hipStream_t stream) {
    const float* x = (const float*)d_in[0];
    const float* gamma = (const float*)d_in[1];
    const float* beta = (const float*)d_in[2];
    const float* wx = (const float*)d_in[3];
    const float* wh = (const float*)d_in[4];
    const float* bs = (const float*)d_in[5];
    float* out = (float*)d_out;

    // workspace layout (16B-aligned); ~25.5 MB
    char* ws = (char*)d_ws;
    f16* xn = (f16*)ws;                        // 16,777,216 B
    f16* wslab = (f16*)(ws + 16777216);        // 2*9*128*104*2 = 479,232 B
    float* cst = (float*)(ws + 17256448);      // 4,194,304 B (private layout)
    f16* hs = (f16*)(ws + 21450752);           // 2 x 2,097,152 B (ping-pong)

    hipMemsetAsync(hs, 0, (size_t)BB * HH * WW * FF * 2, stream);  // h0 = 0 (slot 0)

    ln_kernel<<<1024, 256, 0, stream>>>(x, gamma, beta, xn);
    wprep_kernel<<<936, 256, 0, stream>>>(wx, wh, wslab);
    for (int t = 0; t < TT; t++)
        step_kernel<<<512, 256, 0, stream>>>(xn, wslab, bs, cst, hs, out, t);
}

// Round 6
// 339.957 us; speedup vs baseline: 5.4655x; 1.0729x over previous
//
#include <hip/hip_runtime.h>
#include <hip/hip_fp16.h>

typedef _Float16 f16;
typedef _Float16 f16x8 __attribute__((ext_vector_type(8)));
typedef float f32x4 __attribute__((ext_vector_type(4)));

#define BB 4
#define TT 16
#define HH 64
#define WW 64
#define CC 32
#define FF 64
#define GG 256  // 4F gates

__device__ __forceinline__ float hsig(float z) {
    return fminf(fmaxf(0.2f * z + 0.5f, 0.f), 1.f);
}
__device__ __forceinline__ float tanh_fast(float x) {
    return 1.f - 2.f / (__expf(2.f * x) + 1.f);
}

// ---------------- LayerNorm over C=32: fp32 in -> fp16 out ----------------
__global__ void ln_kernel(const float* __restrict__ x,
                          const float* __restrict__ gamma,
                          const float* __restrict__ beta,
                          f16* __restrict__ xn) {
    __shared__ float sg[CC], sb[CC];
    if (threadIdx.x < CC) sg[threadIdx.x] = gamma[threadIdx.x];
    else if (threadIdx.x < 2 * CC) sb[threadIdx.x - CC] = beta[threadIdx.x - CC];
    __syncthreads();
    int q = blockIdx.x * 256 + threadIdx.x;  // pixel < B*T*H*W = 262144
    const float* xp = x + (size_t)q * CC;
    float v[CC];
    float s = 0.f, s2 = 0.f;
#pragma unroll
    for (int c = 0; c < CC; c += 4) {
        float4 t4 = *(const float4*)(xp + c);
        v[c] = t4.x; v[c + 1] = t4.y; v[c + 2] = t4.z; v[c + 3] = t4.w;
        s += t4.x + t4.y + t4.z + t4.w;
        s2 += t4.x * t4.x + t4.y * t4.y + t4.z * t4.z + t4.w * t4.w;
    }
    float mu = s * (1.f / CC);
    float var = s2 * (1.f / CC) - mu * mu;
    float rs = rsqrtf(var + 1e-3f);
    f16 o[CC];
#pragma unroll
    for (int c = 0; c < CC; c++)
        o[c] = (f16)((v[c] - mu) * rs * sg[c] + sb[c]);
    f16x8* d = (f16x8*)(xn + (size_t)q * CC);
#pragma unroll
    for (int c = 0; c < 4; c++) d[c] = *(f16x8*)&o[c * 8];
}

// ------- Weight transpose: wcat[g][0..288)=Wx taps, [288..864)=Wh taps (k contig) -------
__global__ void wprep_kernel(const float* __restrict__ wx, const float* __restrict__ wh,
                             f16* __restrict__ wcat) {
    int e = blockIdx.x * 256 + threadIdx.x;
    if (e < 9 * CC * GG) {                    // 73728: Wx [tap][c][g] -> [g][tap*32+c]
        int g = e & 255, k = e >> 8;
        wcat[g * 864 + k] = (f16)wx[e];
    } else {
        e -= 9 * CC * GG;
        if (e < 9 * FF * GG) {                // 147456: Wh [tap][f][g] -> [g][288+tap*64+f]
            int g = e & 255, k = e >> 8;
            wcat[g * 864 + 288 + k] = (f16)wh[e];
        }
    }
}

// ---------------- Fused step: z = conv(xn,Wx)+conv(h,Wh)+b; gates; state; pool ----------------
// Grid: 512 = 256 px-tiles x 2 gate-halves. Block: 128 (2 waves) -> 4 blocks/CU (LDS 22.4KB).
// Wave w = fch-16-half; wave tile: 64 px x 64 gates (4 M x 4 cls), acc[4][4] = 64 VGPR.
// B-fragments streamed L2->VGPR with per-chunk immediate offsets (no LDS staging, no
// K-loop barriers); A-fragments from LDS patches. c-state register-resident per step via
// private coalesced cst layout [tile][nhalf][w][lane][16].
__global__ __launch_bounds__(128, 2)
void step_kernel(const f16* __restrict__ xn, const f16* __restrict__ wcat,
                 const float* __restrict__ bs,
                 float* __restrict__ cst, f16* __restrict__ hs,
                 float* __restrict__ out, int t) {
    __shared__ __align__(16) f16 xpatch[100 * 40];   //  8.0 KB (stride 40)
    __shared__ __align__(16) f16 hpatch[100 * 72];   // 14.4 KB (stride 72)
    f16* hstage = xpatch;                            // epilogue reuse: 64 px x 40 f16

    int tile = blockIdx.x >> 1, nhalf = blockIdx.x & 1;
    int bb = tile >> 6, ty = (tile >> 3) & 7, tx = tile & 7;
    int tid = threadIdx.x;
    int lane = tid & 63, w = tid >> 6;
    int quad = lane >> 4, noff = lane & 15;

    int rslot = t & 1;
    const f16* hr = hs + (size_t)rslot * (BB * HH * WW * FF);
    f16* hw = hs + (size_t)(1 - rslot) * (BB * HH * WW * FF);
    const f16* xslice = xn + (size_t)(bb * TT + t) * (HH * WW) * CC;

    // ---- stage patches (zero-padded borders) ----
    {
        f16x8 z = {0, 0, 0, 0, 0, 0, 0, 0};
        for (int j = tid; j < 200; j += 128) {   // xpatch: 100px x 32ch, 16ch per part
            int pix = j >> 1, part = j & 1;
            int py = pix / 10, px = pix % 10;
            int y = ty * 8 - 1 + py, x = tx * 8 - 1 + px;
            f16x8* d = (f16x8*)&xpatch[pix * 40 + part * 16];
            if (y >= 0 && y < HH && x >= 0 && x < WW) {
                const f16x8* s = (const f16x8*)(xslice + ((size_t)y * WW + x) * CC + part * 16);
                d[0] = s[0]; d[1] = s[1];
            } else { d[0] = z; d[1] = z; }
        }
        for (int j = tid; j < 200; j += 128) {   // hpatch: 100px x 64ch, 32ch per part
            int pix = j >> 1, part = j & 1;
            int py = pix / 10, px = pix % 10;
            int y = ty * 8 - 1 + py, x = tx * 8 - 1 + px;
            f16x8* d = (f16x8*)&hpatch[pix * 72 + part * 32];
            if (y >= 0 && y < HH && x >= 0 && x < WW) {
                const f16x8* s = (const f16x8*)(hr + ((size_t)(bb * HH + y) * WW + x) * FF + part * 32);
                d[0] = s[0]; d[1] = s[1]; d[2] = s[2]; d[3] = s[3];
            } else { d[0] = z; d[1] = z; d[2] = z; d[3] = z; }
        }
    }

    // ---- c-state load early (coalesced b128, private layout) ----
    size_t cbase = (size_t)tile * 4096 + (size_t)nhalf * 2048 + w * 1024 + lane * 16;
    f32x4 cs[4];
#pragma unroll
    for (int j = 0; j < 4; j++) cs[j] = (f32x4){0.f, 0.f, 0.f, 0.f};
    if (t > 0) {
#pragma unroll
        for (int j = 0; j < 4; j++) cs[j] = *(const f32x4*)(cst + cbase + j * 4);
    }

    int fch = (nhalf << 5) + (w << 4) + noff;  // f-channel in [0,64)
    float b_i = bs[fch], b_f = bs[64 + fch], b_c = bs[128 + fch], b_o = bs[192 + fch];

    // B-fragment global base pointers (per-chunk offsets are compile-time immediates)
    const f16* bbase[4];
#pragma unroll
    for (int cls = 0; cls < 4; cls++)
        bbase[cls] = wcat + (size_t)((cls << 6) + (nhalf << 5) + (w << 4) + noff) * 864 + (quad << 3);

    // A-fragment base pixel index per M-tile
    int ab[4];
#pragma unroll
    for (int mt = 0; mt < 4; mt++) {
        int m = (mt << 4) + noff;
        ab[mt] = (m >> 3) * 10 + (m & 7);
    }

    f32x4 acc[4][4];
#pragma unroll
    for (int i = 0; i < 4; i++)
#pragma unroll
        for (int j = 0; j < 4; j++) acc[i][j] = (f32x4){0.f, 0.f, 0.f, 0.f};

    __syncthreads();  // patches ready

    // ---- x-conv: chunks 0..8 (K=288), barrier-free ----
#pragma unroll
    for (int c = 0; c < 9; c++) {
        int dy = c / 3, dx = c % 3;
        f16x8 bf[4], a[4];
#pragma unroll
        for (int cls = 0; cls < 4; cls++) bf[cls] = *(const f16x8*)(bbase[cls] + c * 32);
#pragma unroll
        for (int mt = 0; mt < 4; mt++)
            a[mt] = *(const f16x8*)&xpatch[(ab[mt] + dy * 10 + dx) * 40 + (quad << 3)];
#pragma unroll
        for (int cls = 0; cls < 4; cls++)
#pragma unroll
            for (int mt = 0; mt < 4; mt++)
                acc[mt][cls] = __builtin_amdgcn_mfma_f32_16x16x32_f16(a[mt], bf[cls], acc[mt][cls], 0, 0, 0);
    }
    // ---- h-conv: chunks 9..26 (K=576), barrier-free ----
#pragma unroll
    for (int hc = 0; hc < 18; hc++) {
        int tap = hc >> 1, coff = (hc & 1) << 5;
        int dy = tap / 3, dx = tap % 3;
        f16x8 bf[4], a[4];
#pragma unroll
        for (int cls = 0; cls < 4; cls++) bf[cls] = *(const f16x8*)(bbase[cls] + 288 + hc * 32);
#pragma unroll
        for (int mt = 0; mt < 4; mt++)
            a[mt] = *(const f16x8*)&hpatch[(ab[mt] + dy * 10 + dx) * 72 + coff + (quad << 3)];
#pragma unroll
        for (int cls = 0; cls < 4; cls++)
#pragma unroll
            for (int mt = 0; mt < 4; mt++)
                acc[mt][cls] = __builtin_amdgcn_mfma_f32_16x16x32_f16(a[mt], bf[cls], acc[mt][cls], 0, 0, 0);
    }

    __syncthreads();  // all xpatch reads done (hstage aliases it)

    // ---- epilogue: gates + state (c in registers); h -> hstage; coalesced cst store ----
    int fchL = (w << 4) + noff;  // local f-channel [0,32)
#pragma unroll
    for (int mt = 0; mt < 4; mt++) {
        f32x4 cn4;
#pragma unroll
        for (int r = 0; r < 4; r++) {
            int m = (mt << 4) + (quad << 2) + r;  // C/D row = quad*4+reg
            float zi = acc[mt][0][r] + b_i;
            float zf = acc[mt][1][r] + b_f;
            float zc = acc[mt][2][r] + b_c;
            float zo = acc[mt][3][r] + b_o;
            float ig = hsig(zi), fg = hsig(zf), og = hsig(zo);
            float cn = fg * cs[mt][r] + ig * tanh_fast(zc);
            cn4[r] = cn;
            hstage[m * 40 + fchL] = (f16)(og * tanh_fast(cn));
        }
        *(f32x4*)(cst + cbase + mt * 4) = cn4;  // coalesced: lanes 64B apart
    }
    __syncthreads();  // hstage complete

    // coalesced h write: 64 px x 32 f16 (this block's gate-half)
    {
        int px = tid >> 1, part = tid & 1;
        int y = ty * 8 + (px >> 3), x = tx * 8 + (px & 7);
        const f16x8* s = (const f16x8*)&hstage[px * 40 + part * 16];
        f16x8* d = (f16x8*)(hw + ((size_t)(bb * HH + y) * WW + x) * FF + (nhalf << 5) + part * 16);
        d[0] = s[0]; d[1] = s[1];
    }
    // fused 2x2 maxpool: 16 out px x 32 fch -> fp32 out
    {
        int opx = tid >> 3, fp = (tid & 7) * 4;
        int oy2 = opx >> 2, ox2 = opx & 3;
        int p00 = (oy2 * 2) * 8 + ox2 * 2;
        float4 mv;
        float* mp = (float*)&mv;
#pragma unroll
        for (int r = 0; r < 4; r++) {
            mp[r] = fmaxf(fmaxf((float)hstage[p00 * 40 + fp + r], (float)hstage[(p00 + 1) * 40 + fp + r]),
                          fmaxf((float)hstage[(p00 + 8) * 40 + fp + r], (float)hstage[(p00 + 9) * 40 + fp + r]));
        }
        size_t oidx = ((size_t)((bb * TT + t) * 32 + ty * 4 + oy2) * 32 + tx * 4 + ox2) * 64
                    + (nhalf << 5) + fp;
        *(float4*)(out + oidx) = mv;
    }
}

extern "C" void kernel_launch(void* const* d_in, const int* in_sizes, int n_in,
                              void* d_out, int out_size, void* d_ws, size_t ws_size,
                              hipStream_t stream) {
    const float* x = (const float*)d_in[0];
    const float* gamma = (const float*)d_in[1];
    const float* beta = (const float*)d_in[2];
    const float* wx = (const float*)d_in[3];
    const float* wh = (const float*)d_in[4];
    const float* bs = (const float*)d_in[5];
    float* out = (float*)d_out;

    // workspace layout (16B-aligned); ~25.6 MB
    char* ws = (char*)d_ws;
    f16* xn = (f16*)ws;                        // 16,777,216 B
    f16* wcat = (f16*)(ws + 16777216);         // 256*864*2 = 442,368 B
    float* cst = (float*)(ws + 17219584);      // 4,194,304 B (private layout)
    f16* hs = (f16*)(ws + 21413888);           // 2 x 2,097,152 B (ping-pong)

    hipMemsetAsync(hs, 0, (size_t)BB * HH * WW * FF * 2, stream);  // h0 = 0 (slot 0)

    ln_kernel<<<1024, 256, 0, stream>>>(x, gamma, beta, xn);
    wprep_kernel<<<864, 256, 0, stream>>>(wx, wh, wcat);
    for (int t = 0; t < TT; t++)
        step_kernel<<<512, 128, 0, stream>>>(xn, wcat, bs, cst, hs, out, t);
}